// Round 4
// baseline (313.768 us; speedup 1.0000x reference)
//
#include <hip/hip_runtime.h>
#include <math.h>

#define Bsz 64
#define Tn 1000
#define QD 1024
#define MD 512
#define AD 128
#define NF 32
#define KS 31
#define PADc 15

#define TT 64  // t-tile per block in energies kernel

typedef __attribute__((ext_vector_type(8))) short bf16x8;
typedef __attribute__((ext_vector_type(4))) float f32x4;

static __device__ __forceinline__ short f2bf(float x) {
    unsigned u = __float_as_uint(x);
    unsigned r = (u + 0x7fffu + ((u >> 16) & 1u)) >> 16;  // round-to-nearest-even
    return (short)r;
}

static __device__ __forceinline__ float fast_tanh(float x) {
    // tanh(x) = 1 - 2/(exp(2x)+1); saturates correctly for |x| large.
    float e2 = __expf(2.f * x);
    return 1.f - 2.f / (e2 + 1.f);
}

// ---------------------------------------------------------------------------
// Kernel A1: qsum[b][a] = query[b]·Wq[a] + bq[a] + bm[a] + sum_f conv_b[f]*Wloc[a,f]
// ---------------------------------------------------------------------------
__global__ __launch_bounds__(256)
void k_qsum(const float* __restrict__ query, const float* __restrict__ Wq,
            const float* __restrict__ bq, const float* __restrict__ bm,
            const float* __restrict__ conv_b, const float* __restrict__ Wloc,
            float* __restrict__ qsum) {
    int b = blockIdx.x;
    int a = threadIdx.x & 127;
    int half = threadIdx.x >> 7;
    __shared__ float qs[QD];
    __shared__ float red[256];
    for (int i = threadIdx.x; i < QD; i += 256) qs[i] = query[b * QD + i];
    __syncthreads();
    const float4* Wq4 = (const float4*)(Wq + a * QD + half * (QD / 2));
    const float4* qs4 = (const float4*)(qs + half * (QD / 2));
    float acc = 0.f;
#pragma unroll 4
    for (int i = 0; i < QD / 8; ++i) {
        float4 w = Wq4[i];
        float4 q = qs4[i];
        acc += w.x * q.x + w.y * q.y + w.z * q.z + w.w * q.w;
    }
    red[threadIdx.x] = acc;
    __syncthreads();
    if (half == 0) {
        float b2 = 0.f;
        for (int f = 0; f < NF; ++f) b2 += conv_b[f] * Wloc[a * NF + f];
        qsum[b * AD + a] = red[a] + red[a + 128] + bq[a] + bm[a] + b2;
    }
}

// ---------------------------------------------------------------------------
// Kernel A2 (prep): blocks 0..63 cast Wm -> WmB (bf16, [128][512] row-major);
// block 64 computes W2B[a][k] = sum_f conv_w[f,0,k]*Wloc[a,f] (bf16,[128][32])
// ---------------------------------------------------------------------------
__global__ __launch_bounds__(256)
void k_prep(const float* __restrict__ Wm, const float* __restrict__ conv_w,
            const float* __restrict__ Wloc, short* __restrict__ WmB,
            short* __restrict__ W2B) {
    if (blockIdx.x < 64) {
        int base = blockIdx.x * 1024 + threadIdx.x * 4;
        float4 v = *(const float4*)(Wm + base);
        short4 o;
        o.x = f2bf(v.x); o.y = f2bf(v.y); o.z = f2bf(v.z); o.w = f2bf(v.w);
        *(short4*)(WmB + base) = o;
    } else {
        if (threadIdx.x < 128) {
            int a = threadIdx.x;
            for (int k = 0; k < KS; ++k) {
                float s = 0.f;
                for (int f = 0; f < NF; ++f) s += conv_w[f * KS + k] * Wloc[a * NF + f];
                W2B[a * 32 + k] = f2bf(s);
            }
            W2B[a * 32 + KS] = 0;
        }
    }
}

// ---------------------------------------------------------------------------
// Kernel B: fused energies via bf16 MFMA — barrier-free, no LDS.
//   Each lane loads its own A fragment (8 consecutive k of one t-row, 32 B)
//   straight from global and converts to bf16 in-register. B-frags read
//   direct from L2-resident WmB. loc term = extra K-chunk from the Toeplitz
//   of awc. Block: 256 threads = 4 waves; wave w -> t-rows
//   [t0+16w, t0+16w+16) x all 128 a (8 MFMA tiles of 16x16).
// ---------------------------------------------------------------------------
__global__ __launch_bounds__(256)
void k_energies(const float* __restrict__ mem, const float* __restrict__ awc,
                const short* __restrict__ WmB, const short* __restrict__ W2B,
                const float* __restrict__ Wv, const float* __restrict__ bv,
                const float* __restrict__ qsum, float* __restrict__ energies) {
    int b = blockIdx.y;
    int t0 = blockIdx.x * TT;
    int tid = threadIdx.x;
    int wid = tid >> 6;   // wave 0..3
    int lane = tid & 63;
    int m16 = lane & 15;  // A row-in-tile / B col-in-tile
    int q = lane >> 4;    // k-subgroup (frags) / row-subgroup (C/D)

    int t = t0 + wid * 16 + m16;    // this lane's A-row
    int tc = t < Tn ? t : Tn - 1;   // clamped (rows >= Tn never written)

    f32x4 acc[8];
#pragma unroll
    for (int i = 0; i < 8; ++i) acc[i] = (f32x4){0.f, 0.f, 0.f, 0.f};

    const float* arow = mem + (size_t)(b * Tn + tc) * MD + q * 8;
    const short* brow = WmB + m16 * MD + q * 8;

    // ---- location chunk (awc Toeplitz x W2B) ----
    {
        bf16x8 afrag;
#pragma unroll
        for (int j = 0; j < 8; ++j) {
            int kk = q * 8 + j;
            int ts = t + kk - PADc;
            float v = 0.f;
            if (kk < KS && ts >= 0 && ts < Tn) v = awc[b * Tn + ts];
            afrag[j] = f2bf(v);
        }
        const short* b2 = W2B + m16 * 32 + q * 8;
#pragma unroll
        for (int na = 0; na < 8; ++na) {
            bf16x8 bfrag = *(const bf16x8*)(b2 + na * 16 * 32);
            acc[na] = __builtin_amdgcn_mfma_f32_16x16x32_bf16(afrag, bfrag, acc[na], 0, 0, 0);
        }
    }

    // ---- 16 K-chunks of the key GEMM; no barriers, compiler pipelines ----
    for (int c = 0; c < 16; ++c) {
        float4 v0 = *(const float4*)(arow + c * 32);
        float4 v1 = *(const float4*)(arow + c * 32 + 4);
        bf16x8 afrag;
        afrag[0] = f2bf(v0.x); afrag[1] = f2bf(v0.y);
        afrag[2] = f2bf(v0.z); afrag[3] = f2bf(v0.w);
        afrag[4] = f2bf(v1.x); afrag[5] = f2bf(v1.y);
        afrag[6] = f2bf(v1.z); afrag[7] = f2bf(v1.w);
#pragma unroll
        for (int na = 0; na < 8; ++na) {
            bf16x8 bfrag = *(const bf16x8*)(brow + (size_t)na * 16 * MD + c * 32);
            acc[na] = __builtin_amdgcn_mfma_f32_16x16x32_bf16(afrag, bfrag, acc[na], 0, 0, 0);
        }
    }

    // ---- epilogue: tanh, dot Wv, reduce over the 16 a-lanes ----
    // C/D layout: col(a) = na*16 + m16, row(t) = wid*16 + q*4 + r
    float wvv[8], qsv[8];
#pragma unroll
    for (int na = 0; na < 8; ++na) {
        int a = na * 16 + m16;
        wvv[na] = Wv[a];
        qsv[na] = qsum[b * AD + a];
    }
    float bv0 = bv[0];
#pragma unroll
    for (int r = 0; r < 4; ++r) {
        float e = 0.f;
#pragma unroll
        for (int na = 0; na < 8; ++na) e += wvv[na] * fast_tanh(acc[na][r] + qsv[na]);
#pragma unroll
        for (int m2 = 1; m2 < 16; m2 <<= 1) e += __shfl_xor(e, m2, 64);
        if (m16 == 0) {
            int tw = t0 + wid * 16 + q * 4 + r;
            if (tw < Tn) energies[b * Tn + tw] = e + bv0;
        }
    }
}

// ---------------------------------------------------------------------------
// Kernel C: masked softmax over T per batch row.
// ---------------------------------------------------------------------------
__global__ __launch_bounds__(256)
void k_softmax(const float* __restrict__ energies, const unsigned char* __restrict__ mask,
               float* __restrict__ wout) {
    int b = blockIdx.x;
    int tid = threadIdx.x;
    __shared__ float red[256];

    float e[4];
    float lmax = -1e30f;
#pragma unroll
    for (int i = 0; i < 4; ++i) {
        int t = tid + i * 256;
        float v = -1e30f;
        if (t < Tn) {
            v = energies[b * Tn + t];
            if (mask[b * Tn + t]) v = -1e30f;
        }
        e[i] = v;
        lmax = fmaxf(lmax, v);
    }
    red[tid] = lmax;
    __syncthreads();
    for (int s = 128; s > 0; s >>= 1) {
        if (tid < s) red[tid] = fmaxf(red[tid], red[tid + s]);
        __syncthreads();
    }
    float smax = red[0];
    __syncthreads();

    float ex[4];
    float lsum = 0.f;
#pragma unroll
    for (int i = 0; i < 4; ++i) {
        ex[i] = __expf(e[i] - smax);
        lsum += ex[i];
    }
    red[tid] = lsum;
    __syncthreads();
    for (int s = 128; s > 0; s >>= 1) {
        if (tid < s) red[tid] += red[tid + s];
        __syncthreads();
    }
    float inv = 1.f / red[0];
#pragma unroll
    for (int i = 0; i < 4; ++i) {
        int t = tid + i * 256;
        if (t < Tn) wout[b * Tn + t] = ex[i] * inv;
    }
}

// ---------------------------------------------------------------------------
// Kernel D: context[b,m] = sum_t w[b,t] * memory[b,t,m]
// grid (16 t-chunks, 64 b); float2 loads; fp32 atomics (16-way).
// ---------------------------------------------------------------------------
__global__ __launch_bounds__(256)
void k_context(const float* __restrict__ mem, const float* __restrict__ w,
               float* __restrict__ ctx) {
    int tc = blockIdx.x;
    int b = blockIdx.y;
    int tid = threadIdx.x;
    __shared__ float ws[64];
    int tstart = tc * 64;
    if (tid < 64) {
        int tt = tstart + tid;
        ws[tid] = (tt < Tn) ? w[b * Tn + tt] : 0.f;
    }
    __syncthreads();
    const float* mb = mem + (size_t)b * Tn * MD + tid * 2;
    float a0 = 0.f, a1 = 0.f;
    int nrow = (tstart + 64 <= Tn) ? 64 : (Tn - tstart);
    for (int i = 0; i < nrow; ++i) {
        float wv = ws[i];
        float2 v = *(const float2*)(mb + (size_t)(tstart + i) * MD);
        a0 += wv * v.x;
        a1 += wv * v.y;
    }
    atomicAdd(&ctx[b * MD + tid * 2], a0);
    atomicAdd(&ctx[b * MD + tid * 2 + 1], a1);
}

// ---------------------------------------------------------------------------
extern "C" void kernel_launch(void* const* d_in, const int* in_sizes, int n_in,
                              void* d_out, int out_size, void* d_ws, size_t ws_size,
                              hipStream_t stream) {
    const float* query  = (const float*)d_in[0];
    const float* memory = (const float*)d_in[1];
    const float* awc    = (const float*)d_in[2];
    const unsigned char* mask = (const unsigned char*)d_in[3];
    const float* Wq     = (const float*)d_in[4];
    const float* bq     = (const float*)d_in[5];
    const float* Wm     = (const float*)d_in[6];
    const float* bm     = (const float*)d_in[7];
    const float* Wv     = (const float*)d_in[8];
    const float* bv     = (const float*)d_in[9];
    const float* conv_w = (const float*)d_in[10];
    const float* conv_b = (const float*)d_in[11];
    const float* Wloc   = (const float*)d_in[12];

    float* out = (float*)d_out;
    float* ctx = out;             // [64,512]
    float* wout = out + Bsz * MD; // [64,1000]

    float* ws = (float*)d_ws;
    float* qsum  = ws;             // 8192 f
    float* energ = ws + 8192;      // 64000 f -> ends at 288768 B
    short* WmB = (short*)((char*)d_ws + 288768);           // 128 KB bf16
    short* W2B = (short*)((char*)d_ws + 288768 + 131072);  // 8 KB bf16

    hipMemsetAsync(ctx, 0, Bsz * MD * sizeof(float), stream);
    k_qsum<<<dim3(Bsz), dim3(256), 0, stream>>>(query, Wq, bq, bm, conv_b, Wloc, qsum);
    k_prep<<<dim3(65), dim3(256), 0, stream>>>(Wm, conv_w, Wloc, WmB, W2B);
    k_energies<<<dim3((Tn + TT - 1) / TT, Bsz), dim3(256), 0, stream>>>(
        memory, awc, WmB, W2B, Wv, bv, qsum, energ);
    k_softmax<<<dim3(Bsz), dim3(256), 0, stream>>>(energ, mask, wout);
    k_context<<<dim3(16, Bsz), dim3(256), 0, stream>>>(memory, wout, ctx);
}

// Round 5
// 296.891 us; speedup vs baseline: 1.0568x; 1.0568x over previous
//
#include <hip/hip_runtime.h>
#include <math.h>

#define Bsz 64
#define Tn 1000
#define QD 1024
#define MD 512
#define AD 128
#define NF 32
#define KS 31
#define PADc 15

#define TTB 32        // t-rows per block in energies kernel
#define AS_ROW 520    // 512 + 8 shorts pad -> 2-way-max LDS access patterns

typedef __attribute__((ext_vector_type(8))) short bf16x8;
typedef __attribute__((ext_vector_type(4))) float f32x4;

static __device__ __forceinline__ short f2bf(float x) {
    unsigned u = __float_as_uint(x);
    unsigned r = (u + 0x7fffu + ((u >> 16) & 1u)) >> 16;  // round-to-nearest-even
    return (short)r;
}

static __device__ __forceinline__ float fast_tanh(float x) {
    float e2 = __expf(2.f * x);
    return 1.f - 2.f / (e2 + 1.f);
}

// ---------------------------------------------------------------------------
// Kernel A (prep, 97 blocks x 256):
//   blocks 0..31  : Wm -> WmF bf16 fragment-major: slot g=(w*16+c)*64+lane
//                   holds B[a=w*16+(lane&15)][k=c*32+(lane>>4)*8+j], j<8
//   blocks 32..95 : qsum[b][a] = query.Wq + bq + bm + conv_b.Wloc  (b=bid-32)
//   block  96     : W2F bf16 fragment-major for the location chunk
// ---------------------------------------------------------------------------
__global__ __launch_bounds__(256)
void k_prep(const float* __restrict__ Wm, const float* __restrict__ conv_w,
            const float* __restrict__ conv_b, const float* __restrict__ Wloc,
            const float* __restrict__ query, const float* __restrict__ Wq,
            const float* __restrict__ bq, const float* __restrict__ bm,
            short* __restrict__ WmF, short* __restrict__ W2F,
            float* __restrict__ qsum) {
    __shared__ float qs[QD];
    __shared__ float red[256];
    int bid = blockIdx.x;
    if (bid < 32) {
        int g = bid * 256 + threadIdx.x;  // 0..8191 fragment slots
        int wc = g >> 6, l = g & 63;
        int a = (wc >> 4) * 16 + (l & 15);
        int kb = (wc & 15) * 32 + (l >> 4) * 8;
        const float* src = Wm + a * MD + kb;
        float4 v0 = *(const float4*)src;
        float4 v1 = *(const float4*)(src + 4);
        bf16x8 o;
        o[0] = f2bf(v0.x); o[1] = f2bf(v0.y); o[2] = f2bf(v0.z); o[3] = f2bf(v0.w);
        o[4] = f2bf(v1.x); o[5] = f2bf(v1.y); o[6] = f2bf(v1.z); o[7] = f2bf(v1.w);
        *(bf16x8*)(WmF + (size_t)g * 8) = o;
    } else if (bid < 96) {
        int b = bid - 32;
        int a = threadIdx.x & 127;
        int half = threadIdx.x >> 7;
        for (int i = threadIdx.x; i < QD; i += 256) qs[i] = query[b * QD + i];
        __syncthreads();
        const float4* Wq4 = (const float4*)(Wq + a * QD + half * (QD / 2));
        const float4* qs4 = (const float4*)(qs + half * (QD / 2));
        float acc = 0.f;
#pragma unroll 4
        for (int i = 0; i < QD / 8; ++i) {
            float4 w = Wq4[i];
            float4 q = qs4[i];
            acc += w.x * q.x + w.y * q.y + w.z * q.z + w.w * q.w;
        }
        red[threadIdx.x] = acc;
        __syncthreads();
        if (half == 0) {
            float b2 = 0.f;
            for (int f = 0; f < NF; ++f) b2 += conv_b[f] * Wloc[a * NF + f];
            qsum[b * AD + a] = red[a] + red[a + 128] + bq[a] + bm[a] + b2;
        }
    } else {
        // 512 fragment slots, 2 per thread
        for (int s = threadIdx.x * 2; s < threadIdx.x * 2 + 2; ++s) {
            int w = s >> 6, l = s & 63;
            int a = w * 16 + (l & 15);
            int kb = (l >> 4) * 8;
            bf16x8 o;
#pragma unroll
            for (int j = 0; j < 8; ++j) {
                int k = kb + j;
                float sum = 0.f;
                if (k < KS)
                    for (int f = 0; f < NF; ++f) sum += conv_w[f * KS + k] * Wloc[a * NF + f];
                o[j] = f2bf(sum);
            }
            *(bf16x8*)(W2F + s * 8) = o;
        }
    }
}

// ---------------------------------------------------------------------------
// Kernel B: fused energies via bf16 MFMA — all VMEM lane-contiguous.
//   Block 512 thr (8 waves), tile 32 t x 128 a. Wave w owns a in [16w,16w+16).
//   B-frags: 17 coalesced 1KB loads from fragment-major WmF/W2F -> registers.
//   A-panel: 32 consecutive t-rows = contiguous 64KB of mem, staged linearly
//   (coalesced float4), converted to bf16 in LDS [32][520]. One barrier.
//   K-loop: pure ds_read_b128 + MFMA, zero VMEM, zero barriers.
// ---------------------------------------------------------------------------
__global__ __launch_bounds__(512)
void k_energies(const float* __restrict__ mem, const float* __restrict__ awc,
                const short* __restrict__ WmF, const short* __restrict__ W2F,
                const float* __restrict__ Wv, const float* __restrict__ bv,
                const float* __restrict__ qsum, float* __restrict__ energies) {
    __shared__ short As[TTB * AS_ROW];  // 33.3 KB
    __shared__ float ered[8][TTB + 1];

    int b = blockIdx.y;
    int t0 = blockIdx.x * TTB;
    int tid = threadIdx.x;
    int w = tid >> 6;     // wave id: a-slice [16w, 16w+16)
    int lane = tid & 63;
    int m16 = lane & 15;
    int q = lane >> 4;

    // ---- B fragments: coalesced, issued first (L2-resident) ----
    bf16x8 bf[17];
    const bf16x8* bp = (const bf16x8*)WmF;
#pragma unroll
    for (int c = 0; c < 16; ++c) bf[c] = bp[(w * 16 + c) * 64 + lane];
    bf[16] = ((const bf16x8*)W2F)[w * 64 + lane];

    // ---- stage A panel: linear coalesced copy of 32 rows ----
    const float* base = mem + ((size_t)b * Tn + t0) * MD;
#pragma unroll
    for (int r = 0; r < 8; ++r) {
        int i = tid + r * 512;     // float4 slot in the 32x512 panel
        int t = i >> 7;
        int k = (i & 127) * 4;
        float4 v = make_float4(0.f, 0.f, 0.f, 0.f);
        if (t0 + t < Tn) v = *(const float4*)(base + t * MD + k);
        short4 o;
        o.x = f2bf(v.x); o.y = f2bf(v.y); o.z = f2bf(v.z); o.w = f2bf(v.w);
        *(short4*)&As[t * AS_ROW + k] = o;
    }
    __syncthreads();

    // ---- K-loop: LDS afrags x register bfrags ----
    f32x4 acc0 = {0.f, 0.f, 0.f, 0.f}, acc1 = acc0;
#pragma unroll
    for (int c = 0; c < 16; ++c) {
        bf16x8 a0 = *(const bf16x8*)&As[m16 * AS_ROW + c * 32 + q * 8];
        bf16x8 a1 = *(const bf16x8*)&As[(16 + m16) * AS_ROW + c * 32 + q * 8];
        acc0 = __builtin_amdgcn_mfma_f32_16x16x32_bf16(a0, bf[c], acc0, 0, 0, 0);
        acc1 = __builtin_amdgcn_mfma_f32_16x16x32_bf16(a1, bf[c], acc1, 0, 0, 0);
    }
    {   // location chunk: Toeplitz of awc (tiny, L1-resident gathers)
        bf16x8 a0, a1;
        int tA = t0 + m16, tB = tA + 16;
#pragma unroll
        for (int j = 0; j < 8; ++j) {
            int kk = q * 8 + j;
            int s0 = tA + kk - PADc, s1 = tB + kk - PADc;
            float v0 = (kk < KS && s0 >= 0 && s0 < Tn) ? awc[b * Tn + s0] : 0.f;
            float v1 = (kk < KS && s1 >= 0 && s1 < Tn) ? awc[b * Tn + s1] : 0.f;
            a0[j] = f2bf(v0);
            a1[j] = f2bf(v1);
        }
        acc0 = __builtin_amdgcn_mfma_f32_16x16x32_bf16(a0, bf[16], acc0, 0, 0, 0);
        acc1 = __builtin_amdgcn_mfma_f32_16x16x32_bf16(a1, bf[16], acc1, 0, 0, 0);
    }

    // ---- epilogue: tanh, dot Wv over this wave's 16 a, cross-wave reduce ----
    // C/D: col(a-in-slice) = m16, row(t-in-tile) = q*4 + r
    int a = w * 16 + m16;
    float wvv = Wv[a];
    float qsv = qsum[b * AD + a];
#pragma unroll
    for (int r = 0; r < 4; ++r) {
        float e0 = wvv * fast_tanh(acc0[r] + qsv);
        float e1 = wvv * fast_tanh(acc1[r] + qsv);
#pragma unroll
        for (int m2 = 1; m2 < 16; m2 <<= 1) {
            e0 += __shfl_xor(e0, m2, 64);
            e1 += __shfl_xor(e1, m2, 64);
        }
        if (m16 == 0) {
            ered[w][q * 4 + r] = e0;
            ered[w][16 + q * 4 + r] = e1;
        }
    }
    __syncthreads();
    if (tid < TTB) {
        float E = bv[0];
#pragma unroll
        for (int ww = 0; ww < 8; ++ww) E += ered[ww][tid];
        int t = t0 + tid;
        if (t < Tn) energies[b * Tn + t] = E;
    }
}

// ---------------------------------------------------------------------------
// Kernel C: masked softmax over T per batch row; also zero-inits ctx[b].
// ---------------------------------------------------------------------------
__global__ __launch_bounds__(256)
void k_softmax(const float* __restrict__ energies, const unsigned char* __restrict__ mask,
               float* __restrict__ wout, float* __restrict__ ctx) {
    int b = blockIdx.x;
    int tid = threadIdx.x;
    __shared__ float red[256];

    ctx[b * MD + tid] = 0.f;
    ctx[b * MD + 256 + tid] = 0.f;

    float e[4];
    float lmax = -1e30f;
#pragma unroll
    for (int i = 0; i < 4; ++i) {
        int t = tid + i * 256;
        float v = -1e30f;
        if (t < Tn) {
            v = energies[b * Tn + t];
            if (mask[b * Tn + t]) v = -1e30f;
        }
        e[i] = v;
        lmax = fmaxf(lmax, v);
    }
    red[tid] = lmax;
    __syncthreads();
    for (int s = 128; s > 0; s >>= 1) {
        if (tid < s) red[tid] = fmaxf(red[tid], red[tid + s]);
        __syncthreads();
    }
    float smax = red[0];
    __syncthreads();

    float ex[4];
    float lsum = 0.f;
#pragma unroll
    for (int i = 0; i < 4; ++i) {
        ex[i] = __expf(e[i] - smax);
        lsum += ex[i];
    }
    red[tid] = lsum;
    __syncthreads();
    for (int s = 128; s > 0; s >>= 1) {
        if (tid < s) red[tid] += red[tid + s];
        __syncthreads();
    }
    float inv = 1.f / red[0];
#pragma unroll
    for (int i = 0; i < 4; ++i) {
        int t = tid + i * 256;
        if (t < Tn) wout[b * Tn + t] = ex[i] * inv;
    }
}

// ---------------------------------------------------------------------------
// Kernel D: context[b,m] = sum_t w[b,t] * memory[b,t,m]
// grid (16 t-chunks, 64 b); coalesced float2 row reads; fp32 atomics (16-way).
// ---------------------------------------------------------------------------
__global__ __launch_bounds__(256)
void k_context(const float* __restrict__ mem, const float* __restrict__ w,
               float* __restrict__ ctx) {
    int tc = blockIdx.x;
    int b = blockIdx.y;
    int tid = threadIdx.x;
    __shared__ float ws[64];
    int tstart = tc * 64;
    if (tid < 64) {
        int tt = tstart + tid;
        ws[tid] = (tt < Tn) ? w[b * Tn + tt] : 0.f;
    }
    __syncthreads();
    const float* mb = mem + (size_t)b * Tn * MD + tid * 2;
    float a0 = 0.f, a1 = 0.f;
    int nrow = (tstart + 64 <= Tn) ? 64 : (Tn - tstart);
    for (int i = 0; i < nrow; ++i) {
        float wv = ws[i];
        float2 v = *(const float2*)(mb + (size_t)(tstart + i) * MD);
        a0 += wv * v.x;
        a1 += wv * v.y;
    }
    atomicAdd(&ctx[b * MD + tid * 2], a0);
    atomicAdd(&ctx[b * MD + tid * 2 + 1], a1);
}

// ---------------------------------------------------------------------------
extern "C" void kernel_launch(void* const* d_in, const int* in_sizes, int n_in,
                              void* d_out, int out_size, void* d_ws, size_t ws_size,
                              hipStream_t stream) {
    const float* query  = (const float*)d_in[0];
    const float* memory = (const float*)d_in[1];
    const float* awc    = (const float*)d_in[2];
    const unsigned char* mask = (const unsigned char*)d_in[3];
    const float* Wq     = (const float*)d_in[4];
    const float* bq     = (const float*)d_in[5];
    const float* Wm     = (const float*)d_in[6];
    const float* bm     = (const float*)d_in[7];
    const float* Wv     = (const float*)d_in[8];
    const float* bv     = (const float*)d_in[9];
    const float* conv_w = (const float*)d_in[10];
    const float* conv_b = (const float*)d_in[11];
    const float* Wloc   = (const float*)d_in[12];

    float* out = (float*)d_out;
    float* ctx = out;             // [64,512]
    float* wout = out + Bsz * MD; // [64,1000]

    float* ws = (float*)d_ws;
    float* qsum  = ws;             // 8192 f
    float* energ = ws + 8192;      // 64000 f -> ends at byte 288768
    short* WmF = (short*)((char*)d_ws + 288768);           // 65536 shorts = 128 KB
    short* W2F = (short*)((char*)d_ws + 288768 + 131072);  // 4096 shorts = 8 KB

    k_prep<<<dim3(97), dim3(256), 0, stream>>>(Wm, conv_w, conv_b, Wloc, query, Wq,
                                               bq, bm, WmF, W2F, qsum);
    k_energies<<<dim3((Tn + TTB - 1) / TTB, Bsz), dim3(512), 0, stream>>>(
        memory, awc, WmF, W2F, Wv, bv, qsum, energ);
    k_softmax<<<dim3(Bsz), dim3(256), 0, stream>>>(energ, mask, wout, ctx);
    k_context<<<dim3(16, Bsz), dim3(256), 0, stream>>>(memory, wout, ctx);
}